// Round 1
// baseline (21557.054 us; speedup 1.0000x reference)
//
#include <hip/hip_runtime.h>
#include <hip/hip_bf16.h>

typedef __attribute__((ext_vector_type(8))) short short8;
typedef __attribute__((ext_vector_type(4))) float f32x4;

constexpr int BB = 64;    // batch
constexpr int TT = 256;   // time steps
constexpr int II = 512;   // input dim
constexpr int HH = 1024;  // hidden dim

constexpr int NBLK = 256; // 128 blocks per layer
constexpr int NTHR = 512; // 8 waves

constexpr int HTILE = (HH / 8) * BB * 8;  // 65536 elems (tiled h buffer)
constexpr int XTILE = (II / 8) * BB * 8;  // 32768 elems per t

// workspace layout (bytes)
constexpr size_t OFF_FLAGS = 0;
constexpr size_t OFF_WIH0T = 4096;
constexpr size_t OFF_WHH0T = OFF_WIH0T + (size_t)4096 * 512 * 2;
constexpr size_t OFF_WIH1T = OFF_WHH0T + (size_t)4096 * 1024 * 2;
constexpr size_t OFF_WHH1T = OFF_WIH1T + (size_t)4096 * 1024 * 2;
constexpr size_t OFF_XT    = OFF_WHH1T + (size_t)4096 * 1024 * 2;
constexpr size_t OFF_H0D   = OFF_XT + (size_t)TT * XTILE * 2;
constexpr size_t OFF_H1D   = OFF_H0D + (size_t)2 * HTILE * 2;

__device__ __forceinline__ float sigmoid_(float x) {
  return 1.f / (1.f + __expf(-x));
}
__device__ __forceinline__ float tanh_(float x) {
  float ax = fabsf(x);
  float e = __expf(-2.f * ax);
  float t = (1.f - e) / (1.f + e);
  return copysignf(t, x);
}

__global__ void zero_flags(int* f) { f[threadIdx.x] = 0; }

// src [K][N] fp32 -> dst [N][K] bf16
__global__ void transpose_to_bf16(const float* __restrict__ src,
                                  __hip_bfloat16* __restrict__ dst,
                                  int K, int N) {
  __shared__ float tile[64][65];
  const int n0 = blockIdx.x * 64;
  const int k0 = blockIdx.y * 64;
  const int tx = threadIdx.x & 63;
  const int ty = threadIdx.x >> 6;  // 0..3
#pragma unroll
  for (int i = 0; i < 64; i += 4)
    tile[ty + i][tx] = src[(size_t)(k0 + ty + i) * N + n0 + tx];
  __syncthreads();
#pragma unroll
  for (int i = 0; i < 64; i += 4) {
    const int n = ty + i;
    dst[(size_t)(n0 + n) * K + k0 + tx] = __float2bfloat16(tile[tx][n]);
  }
}

// x [B][T][I] fp32 -> xt [T][I/8][B][8] bf16
__global__ void tile_x(const float* __restrict__ x, __hip_bfloat16* __restrict__ xt) {
  const int t = blockIdx.x;
  const int k = threadIdx.x;  // 512
  __hip_bfloat16* o = xt + (size_t)t * XTILE;
  for (int b = 0; b < BB; ++b) {
    float v = x[((size_t)b * TT + t) * II + k];
    o[(k >> 3) * (BB * 8) + b * 8 + (k & 7)] = __float2bfloat16(v);
  }
}

// h0 [2][B][H] fp32 -> tiled bf16 init states
__global__ void init_h(const float* __restrict__ h0, __hip_bfloat16* h0d, __hip_bfloat16* h1d) {
  const int idx = blockIdx.x * 256 + threadIdx.x;  // < 2*BB*HH
  const int l = idx >> 16;
  const int b = (idx >> 10) & 63;
  const int j = idx & 1023;
  __hip_bfloat16 v = __float2bfloat16(h0[idx]);
  __hip_bfloat16* dst = l ? h1d : h0d;
  dst[(j >> 3) * (BB * 8) + b * 8 + (j & 7)] = v;
}

template <int KI, int KW, int LAYER>
__device__ __forceinline__ void scan_impl(
    const __hip_bfloat16* __restrict__ xsrc,  // L0: x_tiled ; L1: unused
    const __hip_bfloat16* __restrict__ WiT,   // [4096][KI]
    const __hip_bfloat16* __restrict__ WhT,   // [4096][HH]
    const float* __restrict__ bias,
    const float* __restrict__ c0_in,
    __hip_bfloat16* h0d, __hip_bfloat16* h1d,
    float* __restrict__ out, int* flags, float* part,
    int bslot, int jbase) {
  const int tid = threadIdx.x;
  const int wave = tid >> 6;
  const int lane = tid & 63;
  const int cc = lane & 15;
  const int lrow = lane >> 4;

  // ---- load W fragments into registers (once) ----
  short8 Bf0[KW], Bf1[KW];
  {
    const int jloc = cc & 7;
    const int gcol0 = ((cc >> 3) + 0) * HH + jbase + jloc;  // i | f
    const int gcol1 = ((cc >> 3) + 2) * HH + jbase + jloc;  // g | o
#pragma unroll
    for (int w = 0; w < KW; ++w) {
      const int kg = wave * (KW * 32) + w * 32 + lrow * 8;
      const __hip_bfloat16 *p0, *p1;
      if (kg < KI) {
        p0 = WiT + (size_t)gcol0 * KI + kg;
        p1 = WiT + (size_t)gcol1 * KI + kg;
      } else {
        p0 = WhT + (size_t)gcol0 * HH + (kg - KI);
        p1 = WhT + (size_t)gcol1 * HH + (kg - KI);
      }
      Bf0[w] = *(const short8*)p0;
      Bf1[w] = *(const short8*)p1;
    }
  }

  const int j = jbase + (cc & 7);
  const float bi = bias[j];
  const float bff = bias[HH + j];
  const float bg = bias[2 * HH + j];
  const float bo = bias[3 * HH + j];
  const int mrow = (wave & 3) * 16 + lrow * 4;  // epilogue rows (waves 0-3)
  float cst[4];
#pragma unroll
  for (int r = 0; r < 4; ++r)
    cst[r] = c0_in[(size_t)LAYER * BB * HH + (size_t)(mrow + r) * HH + j];

  for (int tau = 0; tau <= TT; ++tau) {
    // ---- global barrier: wait until all blocks completed tick tau-1 ----
    if (wave == 0) {
      for (;;) {
        int v0 = __hip_atomic_load(&flags[lane],       __ATOMIC_RELAXED, __HIP_MEMORY_SCOPE_AGENT);
        int v1 = __hip_atomic_load(&flags[lane + 64],  __ATOMIC_RELAXED, __HIP_MEMORY_SCOPE_AGENT);
        int v2 = __hip_atomic_load(&flags[lane + 128], __ATOMIC_RELAXED, __HIP_MEMORY_SCOPE_AGENT);
        int v3 = __hip_atomic_load(&flags[lane + 192], __ATOMIC_RELAXED, __HIP_MEMORY_SCOPE_AGENT);
        int mn = min(min(v0, v1), min(v2, v3));
        if (__all(mn >= tau)) break;
        __builtin_amdgcn_s_sleep(1);
      }
    }
    __syncthreads();
    __threadfence();  // acquire: see other XCDs' h writes

    const bool active = (LAYER == 0) ? (tau < TT) : (tau >= 1);
    if (active) {
      const int s = (LAYER == 0) ? tau : tau - 1;
      const __hip_bfloat16* px;
      const __hip_bfloat16* ph;
      __hip_bfloat16* hout;
      if constexpr (LAYER == 0) {
        px = xsrc + (size_t)s * XTILE;
        ph = h0d + (size_t)(s & 1) * HTILE;
        hout = h0d + (size_t)((s + 1) & 1) * HTILE;
      } else {
        px = h0d + (size_t)(tau & 1) * HTILE;      // layer-0 output of step s
        ph = h1d + (size_t)(s & 1) * HTILE;
        hout = h1d + (size_t)((s + 1) & 1) * HTILE;
      }

      f32x4 acc0[4] = {};
      f32x4 acc1[4] = {};
      const int kb = wave * (KW * 32);
#pragma unroll
      for (int w = 0; w < KW; ++w) {
        const int kg = kb + w * 32;
        const __hip_bfloat16* ab;
        int kc;
        if (kg < KI) { ab = px; kc = (kg >> 3) + lrow; }
        else         { ab = ph; kc = ((kg - KI) >> 3) + lrow; }
        const __hip_bfloat16* arow = ab + (size_t)kc * (BB * 8);
#pragma unroll
        for (int m = 0; m < 4; ++m) {
          short8 a = *(const short8*)(arow + (m * 16 + cc) * 8);
          acc0[m] = __builtin_amdgcn_mfma_f32_16x16x32_bf16(a, Bf0[w], acc0[m], 0, 0, 0);
          acc1[m] = __builtin_amdgcn_mfma_f32_16x16x32_bf16(a, Bf1[w], acc1[m], 0, 0, 0);
        }
      }

      // ---- stage k-partials to LDS ----
#pragma unroll
      for (int m = 0; m < 4; ++m) {
#pragma unroll
        for (int r = 0; r < 4; ++r) {
          part[(wave * 8 + m * 2 + 0) * 272 + (lrow * 4 + r) * 17 + cc] = acc0[m][r];
          part[(wave * 8 + m * 2 + 1) * 272 + (lrow * 4 + r) * 17 + cc] = acc1[m][r];
        }
      }
      __syncthreads();

      // ---- reduce + LSTM cell epilogue on waves 0-3 ----
      if (wave < 4) {
        const int m = wave;
        float red0[4] = {0, 0, 0, 0}, red1[4] = {0, 0, 0, 0};
#pragma unroll
        for (int sw = 0; sw < 8; ++sw) {
#pragma unroll
          for (int r = 0; r < 4; ++r) {
            red0[r] += part[(sw * 8 + m * 2 + 0) * 272 + (lrow * 4 + r) * 17 + cc];
            red1[r] += part[(sw * 8 + m * 2 + 1) * 272 + (lrow * 4 + r) * 17 + cc];
          }
        }
        float fr[4], orr[4];
#pragma unroll
        for (int r = 0; r < 4; ++r) {
          fr[r]  = __shfl_xor(red0[r], 8);
          orr[r] = __shfl_xor(red1[r], 8);
        }
        if (cc < 8) {
#pragma unroll
          for (int r = 0; r < 4; ++r) {
            const int b = mrow + r;
            float iv = sigmoid_(red0[r] + bi);
            float fv = sigmoid_(fr[r] + bff);
            float gv = tanh_(red1[r] + bg);
            float ov = sigmoid_(orr[r] + bo);
            float cn = fv * cst[r] + iv * gv;
            cst[r] = cn;
            float hv = ov * tanh_(cn);
            hout[bslot * 512 + b * 8 + cc] = __float2bfloat16(hv);
            if constexpr (LAYER == 1)
              out[((size_t)b * TT + s) * HH + j] = hv;
            if (s == TT - 1) {
              out[(size_t)BB * TT * HH + (size_t)LAYER * BB * HH + (size_t)b * HH + j] = hv;
              out[(size_t)BB * TT * HH + (size_t)2 * BB * HH + (size_t)LAYER * BB * HH + (size_t)b * HH + j] = cn;
            }
          }
        }
      }
      __threadfence();  // release our h stores
      __syncthreads();
    } else {
      __threadfence();
    }
    if (tid == 0)
      __hip_atomic_store(&flags[blockIdx.x], tau + 1, __ATOMIC_RELEASE, __HIP_MEMORY_SCOPE_AGENT);
  }
}

__global__ __launch_bounds__(NTHR, 2) void lstm_scan(
    const __hip_bfloat16* __restrict__ xt,
    const __hip_bfloat16* __restrict__ Wih0T, const __hip_bfloat16* __restrict__ Whh0T,
    const __hip_bfloat16* __restrict__ Wih1T, const __hip_bfloat16* __restrict__ Whh1T,
    const float* __restrict__ b0, const float* __restrict__ b1,
    const float* __restrict__ c0_in,
    __hip_bfloat16* h0d, __hip_bfloat16* h1d,
    float* __restrict__ out, int* flags) {
  __shared__ float part[17408];  // 8 waves * 8 tiles * (16*17) padded
  const int blk = blockIdx.x;
  const int bslot = blk & 127;
  const int jbase = bslot * 8;
  if ((blk >> 7) == 0)
    scan_impl<512, 6, 0>(xt, Wih0T, Whh0T, b0, c0_in, h0d, h1d, out, flags, part, bslot, jbase);
  else
    scan_impl<1024, 8, 1>(nullptr, Wih1T, Whh1T, b1, c0_in, h0d, h1d, out, flags, part, bslot, jbase);
}

extern "C" void kernel_launch(void* const* d_in, const int* in_sizes, int n_in,
                              void* d_out, int out_size, void* d_ws, size_t ws_size,
                              hipStream_t stream) {
  (void)in_sizes; (void)n_in; (void)out_size; (void)ws_size;
  const float* x    = (const float*)d_in[0];
  const float* h0   = (const float*)d_in[1];
  const float* c0   = (const float*)d_in[2];
  const float* Wih0 = (const float*)d_in[3];
  const float* Whh0 = (const float*)d_in[4];
  const float* b0   = (const float*)d_in[5];
  const float* Wih1 = (const float*)d_in[6];
  const float* Whh1 = (const float*)d_in[7];
  const float* b1   = (const float*)d_in[8];
  float* out = (float*)d_out;
  char* ws = (char*)d_ws;

  int* flags = (int*)(ws + OFF_FLAGS);
  __hip_bfloat16* wih0t = (__hip_bfloat16*)(ws + OFF_WIH0T);
  __hip_bfloat16* whh0t = (__hip_bfloat16*)(ws + OFF_WHH0T);
  __hip_bfloat16* wih1t = (__hip_bfloat16*)(ws + OFF_WIH1T);
  __hip_bfloat16* whh1t = (__hip_bfloat16*)(ws + OFF_WHH1T);
  __hip_bfloat16* xt    = (__hip_bfloat16*)(ws + OFF_XT);
  __hip_bfloat16* h0d   = (__hip_bfloat16*)(ws + OFF_H0D);
  __hip_bfloat16* h1d   = (__hip_bfloat16*)(ws + OFF_H1D);

  zero_flags<<<1, 256, 0, stream>>>(flags);
  transpose_to_bf16<<<dim3(64, 8),  256, 0, stream>>>(Wih0, wih0t, 512, 4096);
  transpose_to_bf16<<<dim3(64, 16), 256, 0, stream>>>(Whh0, whh0t, 1024, 4096);
  transpose_to_bf16<<<dim3(64, 16), 256, 0, stream>>>(Wih1, wih1t, 1024, 4096);
  transpose_to_bf16<<<dim3(64, 16), 256, 0, stream>>>(Whh1, whh1t, 1024, 4096);
  tile_x<<<TT, 512, 0, stream>>>(x, xt);
  init_h<<<512, 256, 0, stream>>>(h0, h0d, h1d);
  lstm_scan<<<NBLK, NTHR, 0, stream>>>(xt, wih0t, whh0t, wih1t, whh1t,
                                       b0, b1, c0, h0d, h1d, out, flags);
}

// Round 2
// 5763.246 us; speedup vs baseline: 3.7404x; 3.7404x over previous
//
#include <hip/hip_runtime.h>
#include <hip/hip_bf16.h>

typedef __attribute__((ext_vector_type(8))) short short8;
typedef __attribute__((ext_vector_type(4))) float f32x4;

constexpr int BB = 64;    // batch
constexpr int TT = 256;   // time steps
constexpr int II = 512;   // input dim
constexpr int HH = 1024;  // hidden dim

constexpr int NBLK = 256; // 128 blocks per layer
constexpr int NTHR = 512; // 8 waves

constexpr int HTILE = (HH / 8) * BB * 8;  // 65536 elems (tiled h buffer)
constexpr int XTILE = (II / 8) * BB * 8;  // 32768 elems per t

// workspace layout (bytes)
constexpr size_t OFF_FLAGS = 0;
constexpr size_t OFF_WIH0T = 4096;
constexpr size_t OFF_WHH0T = OFF_WIH0T + (size_t)4096 * 512 * 2;
constexpr size_t OFF_WIH1T = OFF_WHH0T + (size_t)4096 * 1024 * 2;
constexpr size_t OFF_WHH1T = OFF_WIH1T + (size_t)4096 * 1024 * 2;
constexpr size_t OFF_XT    = OFF_WHH1T + (size_t)4096 * 1024 * 2;
constexpr size_t OFF_H0D   = OFF_XT + (size_t)TT * XTILE * 2;
constexpr size_t OFF_H1D   = OFF_H0D + (size_t)2 * HTILE * 2;

__device__ __forceinline__ float sigmoid_(float x) {
  return 1.f / (1.f + __expf(-x));
}
__device__ __forceinline__ float tanh_(float x) {
  float ax = fabsf(x);
  float e = __expf(-2.f * ax);
  float t = (1.f - e) / (1.f + e);
  return copysignf(t, x);
}

// LLC-coherent (L1/L2-bypassing) 16B fragment load, dword-granular.
__device__ __forceinline__ short8 bypass_frag(const __hip_bfloat16* p) {
  const uint32_t* q = (const uint32_t*)p;
  union { short8 s8; uint32_t u[4]; } f;
#pragma unroll
  for (int i = 0; i < 4; ++i)
    f.u[i] = __hip_atomic_load(q + i, __ATOMIC_RELAXED, __HIP_MEMORY_SCOPE_AGENT);
  return f.s8;
}

__global__ void zero_flags(int* f) { f[threadIdx.x] = 0; }

// src [K][N] fp32 -> dst [N][K] bf16
__global__ void transpose_to_bf16(const float* __restrict__ src,
                                  __hip_bfloat16* __restrict__ dst,
                                  int K, int N) {
  __shared__ float tile[64][65];
  const int n0 = blockIdx.x * 64;
  const int k0 = blockIdx.y * 64;
  const int tx = threadIdx.x & 63;
  const int ty = threadIdx.x >> 6;  // 0..3
#pragma unroll
  for (int i = 0; i < 64; i += 4)
    tile[ty + i][tx] = src[(size_t)(k0 + ty + i) * N + n0 + tx];
  __syncthreads();
#pragma unroll
  for (int i = 0; i < 64; i += 4) {
    const int n = ty + i;
    dst[(size_t)(n0 + n) * K + k0 + tx] = __float2bfloat16(tile[tx][n]);
  }
}

// x [B][T][I] fp32 -> xt [T][I/8][B][8] bf16
__global__ void tile_x(const float* __restrict__ x, __hip_bfloat16* __restrict__ xt) {
  const int t = blockIdx.x;
  const int k = threadIdx.x;  // 512
  __hip_bfloat16* o = xt + (size_t)t * XTILE;
  for (int b = 0; b < BB; ++b) {
    float v = x[((size_t)b * TT + t) * II + k];
    o[(k >> 3) * (BB * 8) + b * 8 + (k & 7)] = __float2bfloat16(v);
  }
}

// h0 [2][B][H] fp32 -> tiled bf16 init states
__global__ void init_h(const float* __restrict__ h0, __hip_bfloat16* h0d, __hip_bfloat16* h1d) {
  const int idx = blockIdx.x * 256 + threadIdx.x;  // < 2*BB*HH
  const int l = idx >> 16;
  const int b = (idx >> 10) & 63;
  const int j = idx & 1023;
  __hip_bfloat16 v = __float2bfloat16(h0[idx]);
  __hip_bfloat16* dst = l ? h1d : h0d;
  dst[(j >> 3) * (BB * 8) + b * 8 + (j & 7)] = v;
}

template <int KI, int KW, int LAYER>
__device__ __forceinline__ void scan_impl(
    const __hip_bfloat16* __restrict__ xsrc,  // L0: x_tiled ; L1: unused
    const __hip_bfloat16* __restrict__ WiT,   // [4096][KI]
    const __hip_bfloat16* __restrict__ WhT,   // [4096][HH]
    const float* __restrict__ bias,
    const float* __restrict__ c0_in,
    __hip_bfloat16* h0d, __hip_bfloat16* h1d,
    float* __restrict__ out, int* flags, float* part,
    int bslot, int jbase) {
  const int tid = threadIdx.x;
  const int wave = tid >> 6;
  const int lane = tid & 63;
  const int cc = lane & 15;
  const int lrow = lane >> 4;

  // ---- load W fragments into registers (once, cached loads) ----
  short8 Bf0[KW], Bf1[KW];
  {
    const int jloc = cc & 7;
    const int gcol0 = ((cc >> 3) + 0) * HH + jbase + jloc;  // i | f
    const int gcol1 = ((cc >> 3) + 2) * HH + jbase + jloc;  // g | o
#pragma unroll
    for (int w = 0; w < KW; ++w) {
      const int kg = wave * (KW * 32) + w * 32 + lrow * 8;
      const __hip_bfloat16 *p0, *p1;
      if (kg < KI) {
        p0 = WiT + (size_t)gcol0 * KI + kg;
        p1 = WiT + (size_t)gcol1 * KI + kg;
      } else {
        p0 = WhT + (size_t)gcol0 * HH + (kg - KI);
        p1 = WhT + (size_t)gcol1 * HH + (kg - KI);
      }
      Bf0[w] = *(const short8*)p0;
      Bf1[w] = *(const short8*)p1;
    }
  }

  const int j = jbase + (cc & 7);
  const float bi = bias[j];
  const float bff = bias[HH + j];
  const float bg = bias[2 * HH + j];
  const float bo = bias[3 * HH + j];
  const int mrow = (wave & 3) * 16 + lrow * 4;  // epilogue rows (waves 0-3)
  float cst[4];
#pragma unroll
  for (int r = 0; r < 4; ++r)
    cst[r] = c0_in[(size_t)LAYER * BB * HH + (size_t)(mrow + r) * HH + j];

  for (int tau = 0; tau <= TT; ++tau) {
    // ---- global barrier: wait until all blocks completed tick tau-1 ----
    if (wave == 0) {
      for (;;) {
        int v0 = __hip_atomic_load(&flags[lane],       __ATOMIC_RELAXED, __HIP_MEMORY_SCOPE_AGENT);
        int v1 = __hip_atomic_load(&flags[lane + 64],  __ATOMIC_RELAXED, __HIP_MEMORY_SCOPE_AGENT);
        int v2 = __hip_atomic_load(&flags[lane + 128], __ATOMIC_RELAXED, __HIP_MEMORY_SCOPE_AGENT);
        int v3 = __hip_atomic_load(&flags[lane + 192], __ATOMIC_RELAXED, __HIP_MEMORY_SCOPE_AGENT);
        int mn = min(min(v0, v1), min(v2, v3));
        if (__all(mn >= tau)) break;
        __builtin_amdgcn_s_sleep(1);
      }
    }
    __syncthreads();  // also a compiler barrier: h loads below can't hoist above the poll

    const bool active = (LAYER == 0) ? (tau < TT) : (tau >= 1);
    if (active) {
      const int s = (LAYER == 0) ? tau : tau - 1;
      const __hip_bfloat16* px;
      const __hip_bfloat16* ph;
      __hip_bfloat16* hout;
      if constexpr (LAYER == 0) {
        px = xsrc + (size_t)s * XTILE;
        ph = h0d + (size_t)(s & 1) * HTILE;
        hout = h0d + (size_t)((s + 1) & 1) * HTILE;
      } else {
        px = h0d + (size_t)(tau & 1) * HTILE;      // layer-0 output of step s
        ph = h1d + (size_t)(s & 1) * HTILE;
        hout = h1d + (size_t)((s + 1) & 1) * HTILE;
      }

      f32x4 acc0[4] = {};
      f32x4 acc1[4] = {};
      const int kb = wave * (KW * 32);
#pragma unroll
      for (int w = 0; w < KW; ++w) {
        const int kg = kb + w * 32;
        const __hip_bfloat16* ab;
        int kc;
        bool hpath;
        if (kg < KI) { ab = px; kc = (kg >> 3) + lrow; hpath = (LAYER == 1); }
        else         { ab = ph; kc = ((kg - KI) >> 3) + lrow; hpath = true; }
        const __hip_bfloat16* arow = ab + (size_t)kc * (BB * 8);
#pragma unroll
        for (int m = 0; m < 4; ++m) {
          short8 a;
          if (hpath) a = bypass_frag(arow + (m * 16 + cc) * 8);
          else       a = *(const short8*)(arow + (m * 16 + cc) * 8);
          acc0[m] = __builtin_amdgcn_mfma_f32_16x16x32_bf16(a, Bf0[w], acc0[m], 0, 0, 0);
          acc1[m] = __builtin_amdgcn_mfma_f32_16x16x32_bf16(a, Bf1[w], acc1[m], 0, 0, 0);
        }
      }

      // ---- stage k-partials to LDS ----
#pragma unroll
      for (int m = 0; m < 4; ++m) {
#pragma unroll
        for (int r = 0; r < 4; ++r) {
          part[(wave * 8 + m * 2 + 0) * 272 + (lrow * 4 + r) * 17 + cc] = acc0[m][r];
          part[(wave * 8 + m * 2 + 1) * 272 + (lrow * 4 + r) * 17 + cc] = acc1[m][r];
        }
      }
      __syncthreads();

      // ---- reduce + LSTM cell epilogue on waves 0-3 ----
      if (wave < 4) {
        const int m = wave;
        float red0[4] = {0, 0, 0, 0}, red1[4] = {0, 0, 0, 0};
#pragma unroll
        for (int sw = 0; sw < 8; ++sw) {
#pragma unroll
          for (int r = 0; r < 4; ++r) {
            red0[r] += part[(sw * 8 + m * 2 + 0) * 272 + (lrow * 4 + r) * 17 + cc];
            red1[r] += part[(sw * 8 + m * 2 + 1) * 272 + (lrow * 4 + r) * 17 + cc];
          }
        }
        float fr[4], orr[4];
#pragma unroll
        for (int r = 0; r < 4; ++r) {
          fr[r]  = __shfl_xor(red0[r], 8);
          orr[r] = __shfl_xor(red1[r], 8);
        }
        if (cc < 8) {
          uint32_t* hq = (uint32_t*)hout;
#pragma unroll
          for (int r = 0; r < 4; ++r) {
            const int b = mrow + r;
            float iv = sigmoid_(red0[r] + bi);
            float fv = sigmoid_(fr[r] + bff);
            float gv = tanh_(red1[r] + bg);
            float ov = sigmoid_(orr[r] + bo);
            float cn = fv * cst[r] + iv * gv;
            cst[r] = cn;
            float hv = ov * tanh_(cn);
            // pack 2 adjacent bf16 cols -> one dword, write-through to LLC
            __hip_bfloat16 hb = __float2bfloat16(hv);
            unsigned short hu = *reinterpret_cast<unsigned short*>(&hb);
            unsigned pu = (unsigned)__shfl_xor((int)hu, 1);
            if ((cc & 1) == 0) {
              uint32_t packed = (uint32_t)hu | ((pu & 0xffffu) << 16);
              __hip_atomic_store(hq + bslot * 256 + b * 4 + (cc >> 1), packed,
                                 __ATOMIC_RELAXED, __HIP_MEMORY_SCOPE_AGENT);
            }
            if constexpr (LAYER == 1)
              out[((size_t)b * TT + s) * HH + j] = hv;
            if (s == TT - 1) {
              out[(size_t)BB * TT * HH + (size_t)LAYER * BB * HH + (size_t)b * HH + j] = hv;
              out[(size_t)BB * TT * HH + (size_t)2 * BB * HH + (size_t)LAYER * BB * HH + (size_t)b * HH + j] = cn;
            }
          }
        }
      }
      // wait for our h write-through stores to be acked at the LLC
      asm volatile("s_waitcnt vmcnt(0)" ::: "memory");
      __syncthreads();  // all waves (incl. storing waves 0-3) done before flag
    }
    if (tid == 0)
      __hip_atomic_store(&flags[blockIdx.x], tau + 1, __ATOMIC_RELAXED, __HIP_MEMORY_SCOPE_AGENT);
  }
}

__global__ __launch_bounds__(NTHR, 2) void lstm_scan(
    const __hip_bfloat16* __restrict__ xt,
    const __hip_bfloat16* __restrict__ Wih0T, const __hip_bfloat16* __restrict__ Whh0T,
    const __hip_bfloat16* __restrict__ Wih1T, const __hip_bfloat16* __restrict__ Whh1T,
    const float* __restrict__ b0, const float* __restrict__ b1,
    const float* __restrict__ c0_in,
    __hip_bfloat16* h0d, __hip_bfloat16* h1d,
    float* __restrict__ out, int* flags) {
  __shared__ float part[17408];  // 8 waves * 8 tiles * (16*17) padded
  const int blk = blockIdx.x;
  const int bslot = blk & 127;
  const int jbase = bslot * 8;
  if ((blk >> 7) == 0)
    scan_impl<512, 6, 0>(xt, Wih0T, Whh0T, b0, c0_in, h0d, h1d, out, flags, part, bslot, jbase);
  else
    scan_impl<1024, 8, 1>(nullptr, Wih1T, Whh1T, b1, c0_in, h0d, h1d, out, flags, part, bslot, jbase);
}

extern "C" void kernel_launch(void* const* d_in, const int* in_sizes, int n_in,
                              void* d_out, int out_size, void* d_ws, size_t ws_size,
                              hipStream_t stream) {
  (void)in_sizes; (void)n_in; (void)out_size; (void)ws_size;
  const float* x    = (const float*)d_in[0];
  const float* h0   = (const float*)d_in[1];
  const float* c0   = (const float*)d_in[2];
  const float* Wih0 = (const float*)d_in[3];
  const float* Whh0 = (const float*)d_in[4];
  const float* b0   = (const float*)d_in[5];
  const float* Wih1 = (const float*)d_in[6];
  const float* Whh1 = (const float*)d_in[7];
  const float* b1   = (const float*)d_in[8];
  float* out = (float*)d_out;
  char* ws = (char*)d_ws;

  int* flags = (int*)(ws + OFF_FLAGS);
  __hip_bfloat16* wih0t = (__hip_bfloat16*)(ws + OFF_WIH0T);
  __hip_bfloat16* whh0t = (__hip_bfloat16*)(ws + OFF_WHH0T);
  __hip_bfloat16* wih1t = (__hip_bfloat16*)(ws + OFF_WIH1T);
  __hip_bfloat16* whh1t = (__hip_bfloat16*)(ws + OFF_WHH1T);
  __hip_bfloat16* xt    = (__hip_bfloat16*)(ws + OFF_XT);
  __hip_bfloat16* h0d   = (__hip_bfloat16*)(ws + OFF_H0D);
  __hip_bfloat16* h1d   = (__hip_bfloat16*)(ws + OFF_H1D);

  zero_flags<<<1, 256, 0, stream>>>(flags);
  transpose_to_bf16<<<dim3(64, 8),  256, 0, stream>>>(Wih0, wih0t, 512, 4096);
  transpose_to_bf16<<<dim3(64, 16), 256, 0, stream>>>(Whh0, whh0t, 1024, 4096);
  transpose_to_bf16<<<dim3(64, 16), 256, 0, stream>>>(Whh1, whh1t, 1024, 4096);
  transpose_to_bf16<<<dim3(64, 16), 256, 0, stream>>>(Wih1, wih1t, 1024, 4096);
  tile_x<<<TT, 512, 0, stream>>>(x, xt);
  init_h<<<512, 256, 0, stream>>>(h0, h0d, h1d);
  lstm_scan<<<NBLK, NTHR, 0, stream>>>(xt, wih0t, whh0t, wih1t, whh1t,
                                       b0, b1, c0, h0d, h1d, out, flags);
}

// Round 3
// 3213.610 us; speedup vs baseline: 6.7080x; 1.7934x over previous
//
#include <hip/hip_runtime.h>
#include <hip/hip_bf16.h>

typedef __attribute__((ext_vector_type(8))) short short8;
typedef __attribute__((ext_vector_type(4))) float f32x4;

constexpr int BB = 64;    // batch
constexpr int TT = 256;   // time steps
constexpr int II = 512;   // input dim
constexpr int HH = 1024;  // hidden dim

constexpr int NBLK = 256; // 128 blocks per layer: 2 batch-halves x 64 col-groups
constexpr int NTHR = 512; // 8 waves

constexpr int HTILE = (HH / 8) * BB * 8;  // 65536 elems (tiled h buffer)
constexpr int XTILE = (II / 8) * BB * 8;  // 32768 elems per t

// workspace layout (bytes)
constexpr size_t OFF_FLAGS = 0;
constexpr size_t OFF_WIH0T = 4096;
constexpr size_t OFF_WHH0T = OFF_WIH0T + (size_t)4096 * 512 * 2;
constexpr size_t OFF_WIH1T = OFF_WHH0T + (size_t)4096 * 1024 * 2;
constexpr size_t OFF_WHH1T = OFF_WIH1T + (size_t)4096 * 1024 * 2;
constexpr size_t OFF_XT    = OFF_WHH1T + (size_t)4096 * 1024 * 2;
constexpr size_t OFF_H0D   = OFF_XT + (size_t)TT * XTILE * 2;
constexpr size_t OFF_H1D   = OFF_H0D + (size_t)2 * HTILE * 2;

__device__ __forceinline__ float sigmoid_(float x) {
  return 1.f / (1.f + __expf(-x));
}
__device__ __forceinline__ float tanh_(float x) {
  float ax = fabsf(x);
  float e = __expf(-2.f * ax);
  float t = (1.f - e) / (1.f + e);
  return copysignf(t, x);
}

__global__ void zero_flags(int* f) { f[threadIdx.x] = 0; }

// src [K][N] fp32 -> dst [N][K] bf16
__global__ void transpose_to_bf16(const float* __restrict__ src,
                                  __hip_bfloat16* __restrict__ dst,
                                  int K, int N) {
  __shared__ float tile[64][65];
  const int n0 = blockIdx.x * 64;
  const int k0 = blockIdx.y * 64;
  const int tx = threadIdx.x & 63;
  const int ty = threadIdx.x >> 6;  // 0..3
#pragma unroll
  for (int i = 0; i < 64; i += 4)
    tile[ty + i][tx] = src[(size_t)(k0 + ty + i) * N + n0 + tx];
  __syncthreads();
#pragma unroll
  for (int i = 0; i < 64; i += 4) {
    const int n = ty + i;
    dst[(size_t)(n0 + n) * K + k0 + tx] = __float2bfloat16(tile[tx][n]);
  }
}

// x [B][T][I] fp32 -> xt [T][I/8][B][8] bf16
__global__ void tile_x(const float* __restrict__ x, __hip_bfloat16* __restrict__ xt) {
  const int t = blockIdx.x;
  const int k = threadIdx.x;  // 512
  __hip_bfloat16* o = xt + (size_t)t * XTILE;
  for (int b = 0; b < BB; ++b) {
    float v = x[((size_t)b * TT + t) * II + k];
    o[(k >> 3) * (BB * 8) + b * 8 + (k & 7)] = __float2bfloat16(v);
  }
}

// h0 [2][B][H] fp32 -> tiled bf16 init states
__global__ void init_h(const float* __restrict__ h0, __hip_bfloat16* h0d, __hip_bfloat16* h1d) {
  const int idx = blockIdx.x * 256 + threadIdx.x;  // < 2*BB*HH
  const int l = idx >> 16;
  const int b = (idx >> 10) & 63;
  const int j = idx & 1023;
  __hip_bfloat16 v = __float2bfloat16(h0[idx]);
  __hip_bfloat16* dst = l ? h1d : h0d;
  dst[(j >> 3) * (BB * 8) + b * 8 + (j & 7)] = v;
}

template <int KI, int KW, int LAYER>
__device__ __forceinline__ void scan_impl(
    const __hip_bfloat16* __restrict__ xsrc,  // L0: x_tiled ; L1: unused
    const __hip_bfloat16* __restrict__ WiT,   // [4096][KI]
    const __hip_bfloat16* __restrict__ WhT,   // [4096][HH]
    const float* __restrict__ bias,
    const float* __restrict__ c0_in,
    __hip_bfloat16* h0d, __hip_bfloat16* h1d,
    float* __restrict__ out, int* flags, f32x4 (*part)[2][4][64],
    int bhalf, int jbase) {
  const int tid = threadIdx.x;
  const int wave = tid >> 6;
  const int lane = tid & 63;
  const int cc = lane & 15;    // MFMA col / batch-row within tile
  const int lrow = lane >> 4;  // k-chunk select

  const int kbase = wave * (KW * 32);

  // ---- load W fragments into registers (once, cached loads) ----
  // Bf[w][g]: B-fragment for gate g (cols = jbase..jbase+15), k = kbase+w*32
  short8 Bf[KW][4];
#pragma unroll
  for (int w = 0; w < KW; ++w) {
    const int kg = kbase + w * 32 + lrow * 8;
#pragma unroll
    for (int g = 0; g < 4; ++g) {
      const int gcol = g * HH + jbase + cc;
      const __hip_bfloat16* p;
      if (kg < KI) p = WiT + (size_t)gcol * KI + kg;
      else         p = WhT + (size_t)gcol * HH + (kg - KI);
      Bf[w][g] = *(const short8*)p;
    }
  }

  // ---- epilogue-lane constants (valid for tid < 128) ----
  const int em = (tid >> 6) & 1;                       // m-tile
  const int ej = jbase + (lane & 15);                  // gate column j
  const int eb0 = bhalf * 32 + em * 16 + (lane >> 4) * 4;  // first batch row
  const float bi = bias[ej];
  const float bf_ = bias[HH + ej];
  const float bg = bias[2 * HH + ej];
  const float bo = bias[3 * HH + ej];
  float cst[4];
#pragma unroll
  for (int r = 0; r < 4; ++r)
    cst[r] = c0_in[(size_t)LAYER * BB * HH + (size_t)(eb0 + r) * HH + ej];

  for (int tau = 0; tau <= TT; ++tau) {
    // ---- global barrier: wait until all blocks completed tick tau-1 ----
    if (wave == 0) {
      for (;;) {
        int v0 = __hip_atomic_load(&flags[lane],       __ATOMIC_RELAXED, __HIP_MEMORY_SCOPE_AGENT);
        int v1 = __hip_atomic_load(&flags[lane + 64],  __ATOMIC_RELAXED, __HIP_MEMORY_SCOPE_AGENT);
        int v2 = __hip_atomic_load(&flags[lane + 128], __ATOMIC_RELAXED, __HIP_MEMORY_SCOPE_AGENT);
        int v3 = __hip_atomic_load(&flags[lane + 192], __ATOMIC_RELAXED, __HIP_MEMORY_SCOPE_AGENT);
        int mn = min(min(v0, v1), min(v2, v3));
        if (__all(mn >= tau)) break;
        __builtin_amdgcn_s_sleep(4);
      }
    }
    __syncthreads();  // compiler+exec barrier: nothing below hoists above poll

    const bool active = (LAYER == 0) ? (tau < TT) : (tau >= 1);
    if (active) {
      const int s = (LAYER == 0) ? tau : tau - 1;
      const __hip_bfloat16* px;
      const __hip_bfloat16* ph;
      __hip_bfloat16* hout;
      if constexpr (LAYER == 0) {
        px = xsrc + (size_t)s * XTILE;
        ph = h0d + (size_t)(s & 1) * HTILE;
        hout = h0d + (size_t)((s + 1) & 1) * HTILE;
      } else {
        px = h0d + (size_t)(tau & 1) * HTILE;      // layer-0 output of step s
        ph = h1d + (size_t)(s & 1) * HTILE;
        hout = h1d + (size_t)((s + 1) & 1) * HTILE;
      }

      // ---- software-pipelined A-fragment loads (16B, LLC-coherent) + MFMA ----
      f32x4 acc[2][4] = {};
      short8 abuf[3][2];

      auto issue_pair = [&](int w, short8* dst) {
        const int kg = kbase + w * 32;
        const __hip_bfloat16* ab;
        int kc;
        bool cached;
        if (kg < KI) { ab = px; kc = (kg >> 3) + lrow; cached = (LAYER == 0); }
        else         { ab = ph; kc = ((kg - KI) >> 3) + lrow; cached = false; }
#pragma unroll
        for (int m = 0; m < 2; ++m) {
          const __hip_bfloat16* p =
              ab + (size_t)kc * (BB * 8) + (size_t)(bhalf * 32 + m * 16 + cc) * 8;
          if (cached)
            asm volatile("global_load_dwordx4 %0, %1, off" : "=v"(dst[m]) : "v"(p));
          else
            asm volatile("global_load_dwordx4 %0, %1, off sc0 sc1" : "=v"(dst[m]) : "v"(p));
        }
      };

#pragma unroll
      for (int w = 0; w < 3; ++w) issue_pair(w, abuf[w]);

#pragma unroll
      for (int w = 0; w < KW; ++w) {
        const int rem = KW - 1 - w;
        if (rem >= 2)      asm volatile("s_waitcnt vmcnt(4)" ::: "memory");
        else if (rem == 1) asm volatile("s_waitcnt vmcnt(2)" ::: "memory");
        else               asm volatile("s_waitcnt vmcnt(0)" ::: "memory");
        __builtin_amdgcn_sched_barrier(0);
#pragma unroll
        for (int m = 0; m < 2; ++m)
#pragma unroll
          for (int g = 0; g < 4; ++g)
            acc[m][g] = __builtin_amdgcn_mfma_f32_16x16x32_bf16(
                abuf[w % 3][m], Bf[w][g], acc[m][g], 0, 0, 0);
        if (w + 3 < KW) issue_pair(w + 3, abuf[w % 3]);
      }

      // ---- stage k-partials to LDS ----
#pragma unroll
      for (int m = 0; m < 2; ++m)
#pragma unroll
        for (int g = 0; g < 4; ++g)
          part[wave][m][g][lane] = acc[m][g];
      __syncthreads();

      // ---- reduce + LSTM cell epilogue on waves 0-1 (128 threads) ----
      if (tid < 128) {
        f32x4 reds[4];
#pragma unroll
        for (int g = 0; g < 4; ++g) {
          f32x4 sum = part[0][em][g][lane];
#pragma unroll
          for (int w = 1; w < 8; ++w) {
            f32x4 t = part[w][em][g][lane];
#pragma unroll
            for (int r = 0; r < 4; ++r) sum[r] += t[r];
          }
          reds[g] = sum;
        }
        uint32_t* hq = (uint32_t*)hout;
#pragma unroll
        for (int r = 0; r < 4; ++r) {
          const int b = eb0 + r;
          float iv = sigmoid_(reds[0][r] + bi);
          float fv = sigmoid_(reds[1][r] + bf_);
          float gv = tanh_(reds[2][r] + bg);
          float ov = sigmoid_(reds[3][r] + bo);
          float cn = fv * cst[r] + iv * gv;
          cst[r] = cn;
          float hv = ov * tanh_(cn);
          // pack 2 adjacent bf16 cols -> one dword, write-through to LLC
          __hip_bfloat16 hb = __float2bfloat16(hv);
          unsigned short hu = *reinterpret_cast<unsigned short*>(&hb);
          unsigned pu = (unsigned)__shfl_xor((int)hu, 1);
          if ((lane & 1) == 0) {
            uint32_t packed = (uint32_t)hu | ((pu & 0xffffu) << 16);
            __hip_atomic_store(hq + (ej >> 3) * 256 + b * 4 + ((ej & 7) >> 1), packed,
                               __ATOMIC_RELAXED, __HIP_MEMORY_SCOPE_AGENT);
          }
          if constexpr (LAYER == 1)
            out[((size_t)b * TT + s) * HH + ej] = hv;
          if (s == TT - 1) {
            out[(size_t)BB * TT * HH + (size_t)LAYER * BB * HH + (size_t)b * HH + ej] = hv;
            out[(size_t)BB * TT * HH + (size_t)2 * BB * HH + (size_t)LAYER * BB * HH + (size_t)b * HH + ej] = cn;
          }
        }
      }
      // wait for our stores to be acked, then block-wide rendezvous
      asm volatile("s_waitcnt vmcnt(0)" ::: "memory");
      __syncthreads();
    }
    if (tid == 0)
      __hip_atomic_store(&flags[blockIdx.x], tau + 1, __ATOMIC_RELAXED, __HIP_MEMORY_SCOPE_AGENT);
  }
}

__global__ __launch_bounds__(NTHR, 2) void lstm_scan(
    const __hip_bfloat16* __restrict__ xt,
    const __hip_bfloat16* __restrict__ Wih0T, const __hip_bfloat16* __restrict__ Whh0T,
    const __hip_bfloat16* __restrict__ Wih1T, const __hip_bfloat16* __restrict__ Whh1T,
    const float* __restrict__ b0, const float* __restrict__ b1,
    const float* __restrict__ c0_in,
    __hip_bfloat16* h0d, __hip_bfloat16* h1d,
    float* __restrict__ out, int* flags) {
  __shared__ f32x4 part[8][2][4][64];  // 64 KiB
  const int blk = blockIdx.x;
  const int jslot = blk & 63;
  const int bhalf = (blk >> 6) & 1;
  const int jbase = jslot * 16;
  if ((blk >> 7) == 0)
    scan_impl<512, 6, 0>(xt, Wih0T, Whh0T, b0, c0_in, h0d, h1d, out, flags, part, bhalf, jbase);
  else
    scan_impl<1024, 8, 1>(nullptr, Wih1T, Whh1T, b1, c0_in, h0d, h1d, out, flags, part, bhalf, jbase);
}

extern "C" void kernel_launch(void* const* d_in, const int* in_sizes, int n_in,
                              void* d_out, int out_size, void* d_ws, size_t ws_size,
                              hipStream_t stream) {
  (void)in_sizes; (void)n_in; (void)out_size; (void)ws_size;
  const float* x    = (const float*)d_in[0];
  const float* h0   = (const float*)d_in[1];
  const float* c0   = (const float*)d_in[2];
  const float* Wih0 = (const float*)d_in[3];
  const float* Whh0 = (const float*)d_in[4];
  const float* b0   = (const float*)d_in[5];
  const float* Wih1 = (const float*)d_in[6];
  const float* Whh1 = (const float*)d_in[7];
  const float* b1   = (const float*)d_in[8];
  float* out = (float*)d_out;
  char* ws = (char*)d_ws;

  int* flags = (int*)(ws + OFF_FLAGS);
  __hip_bfloat16* wih0t = (__hip_bfloat16*)(ws + OFF_WIH0T);
  __hip_bfloat16* whh0t = (__hip_bfloat16*)(ws + OFF_WHH0T);
  __hip_bfloat16* wih1t = (__hip_bfloat16*)(ws + OFF_WIH1T);
  __hip_bfloat16* whh1t = (__hip_bfloat16*)(ws + OFF_WHH1T);
  __hip_bfloat16* xt    = (__hip_bfloat16*)(ws + OFF_XT);
  __hip_bfloat16* h0d   = (__hip_bfloat16*)(ws + OFF_H0D);
  __hip_bfloat16* h1d   = (__hip_bfloat16*)(ws + OFF_H1D);

  zero_flags<<<1, 256, 0, stream>>>(flags);
  transpose_to_bf16<<<dim3(64, 8),  256, 0, stream>>>(Wih0, wih0t, 512, 4096);
  transpose_to_bf16<<<dim3(64, 16), 256, 0, stream>>>(Whh0, whh0t, 1024, 4096);
  transpose_to_bf16<<<dim3(64, 16), 256, 0, stream>>>(Wih1, wih1t, 1024, 4096);
  transpose_to_bf16<<<dim3(64, 16), 256, 0, stream>>>(Whh1, whh1t, 1024, 4096);
  tile_x<<<TT, 512, 0, stream>>>(x, xt);
  init_h<<<512, 256, 0, stream>>>(h0, h0d, h1d);
  lstm_scan<<<NBLK, NTHR, 0, stream>>>(xt, wih0t, whh0t, wih1t, whh1t,
                                       b0, b1, c0, h0d, h1d, out, flags);
}